// Round 3
// baseline (60495.544 us; speedup 1.0000x reference)
//
#include <hip/hip_runtime.h>
#include <hip/hip_cooperative_groups.h>
#include <math.h>

// Problem constants
#define T_ENC 512
#define NB    128
#define LDEC  256
#define VOCD  34

// ---------------- workspace layout (floats) — identical to R1 ----------------
#define OFF_W1P   0
#define OFF_EG    1310720
#define OFF_W2P   1380352
#define OFF_B2    1708032
#define OFF_WOT   1708544
#define OFF_ST    1717248
#define ST_H1T0   0
#define ST_H1T1   65536
#define ST_C1T    131072
#define ST_H2T0   196608
#define ST_H2T1   212992
#define ST_C2T    229376
#define ST_H2ROW  245760
#define ST_CTXT   262144
#define ST_SIZE   278528

__device__ __forceinline__ float sigf(float x) { return 1.0f / (1.0f + expf(-x)); }

// ---- pack kernels (verbatim R1; proven) ----
__global__ __launch_bounds__(256) void pack_w1(const float* __restrict__ Wih1,
                                               const float* __restrict__ Whh1,
                                               float* __restrict__ W1P) {
  int idx = blockIdx.x * 256 + threadIdx.x;   // < 1,310,720
  int b = idx / 5120, r = idx % 5120;
  int k = r >> 3, j = r & 7;
  int q = j & 3, u = 2 * b + (j >> 2);
  int g = q * 512 + u;
  float v = (k < 128) ? Wih1[g * 384 + 256 + k]
                      : Whh1[g * 512 + (k - 128)];
  W1P[idx] = v;
}

__global__ __launch_bounds__(256) void pack_eg(const float* __restrict__ emb,
                                               const float* __restrict__ Wih1,
                                               const float* __restrict__ bih1,
                                               const float* __restrict__ bhh1,
                                               float* __restrict__ EG) {
  int idx = blockIdx.x * 256 + threadIdx.x;   // < 69,632
  int v = idx / 2048, gl = idx % 2048;
  int u = gl >> 2, q = gl & 3;
  int g = q * 512 + u;
  float acc = bih1[g] + bhh1[g];
  const float* e = emb + v * 256;
  const float* w = Wih1 + g * 384;
  for (int k = 0; k < 256; k++) acc += e[k] * w[k];
  EG[idx] = acc;
}

__global__ __launch_bounds__(256) void pack_w2(const float* __restrict__ Wih2,
                                               const float* __restrict__ Whh2,
                                               float* __restrict__ W2P) {
  int idx = blockIdx.x * 256 + threadIdx.x;   // < 327,680
  int b = idx / 5120, r = idx % 5120;
  int k = r >> 3, j = r & 7;
  int q = j & 3, u = 2 * b + (j >> 2);
  int g = q * 128 + u;
  W2P[idx] = (k < 512) ? Wih2[g * 512 + k] : Whh2[g * 128 + (k - 512)];
}

__global__ __launch_bounds__(256) void pack_misc(const float* __restrict__ Wout,
                                                 const float* __restrict__ bih2,
                                                 const float* __restrict__ bhh2,
                                                 float* __restrict__ WoT,
                                                 float* __restrict__ B2) {
  int idx = blockIdx.x * 256 + threadIdx.x;
  if (idx < 8704) {
    int k = idx / 34, v = idx % 34;
    WoT[idx] = Wout[v * 256 + k];
  } else if (idx < 9216) {
    int j = idx - 8704;
    int u = j >> 2, q = j & 3;
    int g = q * 128 + u;
    B2[j] = bih2[g] + bhh2[g];
  }
}

// ---------------- persistent cooperative main kernel ----------------
// Phase bodies are R1's proven kernels, inlined; weights staged to LDS per step.
__global__ void __launch_bounds__(256, 1) decoder_main(
    const float* __restrict__ key, const float* __restrict__ values,
    const int* __restrict__ lens, const int* __restrict__ text,
    const float* __restrict__ W1P, const float* __restrict__ EG,
    const float* __restrict__ W2P, const float* __restrict__ B2,
    const float* __restrict__ WoT, const float* __restrict__ bout,
    float* __restrict__ h1T0, float* __restrict__ h1T1, float* __restrict__ c1T,
    float* __restrict__ h2T0, float* __restrict__ h2T1, float* __restrict__ c2T,
    float* __restrict__ h2row, float* __restrict__ ctxT, float* __restrict__ out)
{
  cooperative_groups::grid_group grid = cooperative_groups::this_grid();

  __shared__ float4 wsv[1280];
  __shared__ float es[512];
  __shared__ float red[256];
  __shared__ float h2s[128];
  __shared__ float ctxs[128];
  __shared__ float pr[68];

  const int bid = blockIdx.x, tid = threadIdx.x;
  const int n = tid & 127, half = tid >> 7;
  const int cn = bid;
  const int clen = (cn < 128) ? lens[cn] : 0;

  for (int t = 0; t < LDEC; t++) {
    const float* h1_old = (t & 1) ? h1T1 : h1T0;
    float*       h1_new = (t & 1) ? h1T0 : h1T1;
    const float* h2_old = (t & 1) ? h2T1 : h2T0;
    float*       h2_new = (t & 1) ? h2T0 : h2T1;

    // ================= phase A (all 256 blocks): gates1 + LSTM1 =================
    {
      const float4* Wp = (const float4*)W1P + bid * 1280;
      for (int i = tid; i < 1280; i += 256) wsv[i] = Wp[i];
      __syncthreads();
      int u = 2 * bid + half;
      int tok = text[n * LDEC + t];
      const float* eg = EG + tok * 2048 + u * 4;
      float a0 = eg[0], a1 = eg[1], a2 = eg[2], a3 = eg[3];
#pragma unroll 4
      for (int k = 0; k < 128; k++) {            // ctx part
        float xv = ctxT[k * 128 + n];
        float4 w = wsv[k * 2 + half];
        a0 += xv * w.x; a1 += xv * w.y; a2 += xv * w.z; a3 += xv * w.w;
      }
#pragma unroll 4
      for (int k = 0; k < 512; k++) {            // h1 recurrent part
        float xv = h1_old[k * 128 + n];
        float4 w = wsv[(128 + k) * 2 + half];
        a0 += xv * w.x; a1 += xv * w.y; a2 += xv * w.z; a3 += xv * w.w;
      }
      float ig = sigf(a0), fg = sigf(a1), gg = tanhf(a2), og = sigf(a3);
      float c = fg * c1T[u * 128 + n] + ig * gg;
      float h = og * tanhf(c);
      c1T[u * 128 + n] = c;
      h1_new[u * 128 + n] = h;
    }
    grid.sync();

    // ================= phase B (blocks 0..63): gates2 + LSTM2 =================
    if (bid < 64) {
      const float4* Wp = (const float4*)W2P + bid * 1280;
      for (int i = tid; i < 1280; i += 256) wsv[i] = Wp[i];
      __syncthreads();
      int u = 2 * bid + half;
      const float* bb = B2 + u * 4;
      float a0 = bb[0], a1 = bb[1], a2 = bb[2], a3 = bb[3];
#pragma unroll 4
      for (int k = 0; k < 512; k++) {            // h1 input part
        float xv = h1_new[k * 128 + n];
        float4 w = wsv[k * 2 + half];
        a0 += xv * w.x; a1 += xv * w.y; a2 += xv * w.z; a3 += xv * w.w;
      }
#pragma unroll 4
      for (int k = 0; k < 128; k++) {            // h2 recurrent part
        float xv = h2_old[k * 128 + n];
        float4 w = wsv[(512 + k) * 2 + half];
        a0 += xv * w.x; a1 += xv * w.y; a2 += xv * w.z; a3 += xv * w.w;
      }
      float ig = sigf(a0), fg = sigf(a1), gg = tanhf(a2), og = sigf(a3);
      float c = fg * c2T[u * 128 + n] + ig * gg;
      float h = og * tanhf(c);
      c2T[u * 128 + n] = c;
      h2_new[u * 128 + n] = h;
      h2row[n * 128 + u] = h;
    }
    grid.sync();

    // ================= phase C (blocks 0..127): attention + projection ==========
    if (cn < 128) {
      if (tid < 128) h2s[tid] = h2row[cn * 128 + tid];
      __syncthreads();
      float lmax = -1e30f;
      for (int tt = tid; tt < clen; tt += 256) {
        const float4* kr = (const float4*)(key + ((size_t)tt * 128 + cn) * 128);
        float acc = 0.0f;
#pragma unroll 8
        for (int k = 0; k < 32; k++) {
          float4 kv = kr[k];
          acc += kv.x * h2s[4 * k] + kv.y * h2s[4 * k + 1] + kv.z * h2s[4 * k + 2] + kv.w * h2s[4 * k + 3];
        }
        es[tt] = acc;
        lmax = fmaxf(lmax, acc);
      }
      red[tid] = lmax; __syncthreads();
      for (int s = 128; s > 0; s >>= 1) { if (tid < s) red[tid] = fmaxf(red[tid], red[tid + s]); __syncthreads(); }
      float m = red[0];
      __syncthreads();
      float lsum = 0.0f;
      for (int tt = tid; tt < clen; tt += 256) {
        float p = expf(es[tt] - m);
        es[tt] = p;
        lsum += p;
      }
      red[tid] = lsum; __syncthreads();
      for (int s = 128; s > 0; s >>= 1) { if (tid < s) red[tid] += red[tid + s]; __syncthreads(); }
      float S = red[0];
      __syncthreads();
      {
        int v = tid & 127, tpar = tid >> 7;
        float acc = 0.0f;
        for (int tt = tpar; tt < clen; tt += 2) {
          acc += es[tt] * values[((size_t)tt * 128 + cn) * 128 + v];
        }
        red[tid] = acc;
      }
      __syncthreads();
      if (tid < 128) {
        float cv = (red[tid] + red[tid + 128]) / S;
        ctxs[tid] = cv;
        ctxT[tid * 128 + cn] = cv;
      }
      __syncthreads();
      if (tid < 68) {
        int vv = tid % 34, part = tid / 34;
        const float* src = part ? ctxs : h2s;
        const float* wcol = WoT + (part ? 128 * 34 : 0);
        float a = 0.0f;
#pragma unroll 8
        for (int k2 = 0; k2 < 128; k2++) a += src[k2] * wcol[k2 * 34 + vv];
        pr[tid] = a;
      }
      __syncthreads();
      if (tid < 34) {
        out[(size_t)cn * (LDEC * VOCD) + t * VOCD + tid] = bout[tid] + pr[tid] + pr[34 + tid];
      }
      __syncthreads();
    }
    grid.sync();
  }
}

extern "C" void kernel_launch(void* const* d_in, const int* in_sizes, int n_in,
                              void* d_out, int out_size, void* d_ws, size_t ws_size,
                              hipStream_t stream) {
  const float* key    = (const float*)d_in[0];
  const float* values = (const float*)d_in[1];
  const int*   lens   = (const int*)d_in[2];
  const int*   text   = (const int*)d_in[3];
  const float* emb    = (const float*)d_in[4];
  const float* Wih1   = (const float*)d_in[5];
  const float* Whh1   = (const float*)d_in[6];
  const float* bih1   = (const float*)d_in[7];
  const float* bhh1   = (const float*)d_in[8];
  const float* Wih2   = (const float*)d_in[9];
  const float* Whh2   = (const float*)d_in[10];
  const float* bih2   = (const float*)d_in[11];
  const float* bhh2   = (const float*)d_in[12];
  const float* Wout   = (const float*)d_in[13];
  const float* bout   = (const float*)d_in[14];

  float* ws   = (float*)d_ws;
  float* W1P  = ws + OFF_W1P;
  float* EG   = ws + OFF_EG;
  float* W2P  = ws + OFF_W2P;
  float* B2   = ws + OFF_B2;
  float* WoT  = ws + OFF_WOT;
  float* st   = ws + OFF_ST;
  float* h1T0 = st + ST_H1T0;
  float* h1T1 = st + ST_H1T1;
  float* c1T  = st + ST_C1T;
  float* h2T0 = st + ST_H2T0;
  float* h2T1 = st + ST_H2T1;
  float* c2T  = st + ST_C2T;
  float* h2row= st + ST_H2ROW;
  float* ctxT = st + ST_CTXT;
  float* out  = (float*)d_out;

  hipMemsetAsync(st, 0, (size_t)ST_SIZE * sizeof(float), stream);

  pack_w1  <<<5120, 256, 0, stream>>>(Wih1, Whh1, W1P);
  pack_eg  <<<272,  256, 0, stream>>>(emb, Wih1, bih1, bhh1, EG);
  pack_w2  <<<1280, 256, 0, stream>>>(Wih2, Whh2, W2P);
  pack_misc<<<36,   256, 0, stream>>>(Wout, bih2, bhh2, WoT, B2);

  void* args[] = {
    (void*)&key, (void*)&values, (void*)&lens, (void*)&text,
    (void*)&W1P, (void*)&EG, (void*)&W2P, (void*)&B2, (void*)&WoT, (void*)&bout,
    (void*)&h1T0, (void*)&h1T1, (void*)&c1T,
    (void*)&h2T0, (void*)&h2T1, (void*)&c2T,
    (void*)&h2row, (void*)&ctxT, (void*)&out
  };
  hipLaunchCooperativeKernel((const void*)decoder_main, dim3(256), dim3(256),
                             args, 0, stream);
}

// Round 8
// 23068.137 us; speedup vs baseline: 2.6225x; 2.6225x over previous
//
#include <hip/hip_runtime.h>
#include <math.h>

#define LDEC 256
#define VOCD 34

typedef __attribute__((ext_vector_type(8))) short bf16x8;
typedef __attribute__((ext_vector_type(4))) float f32x4;

// ---------------- workspace layout (byte offsets), total 7,983,104 B ----------------
#define OFF_W1H  0u          // bf16 [2048 m][640 k] hi  (m = u*4+q)
#define OFF_W1L  2621440u    // bf16 [2048 m][640 k] lo
#define OFF_W2H  5242880u    // bf16 [512 m][640 k] hi
#define OFF_W2L  5898240u    // bf16 [512 m][640 k] lo
#define OFF_EG   6553600u    // f32  [34 tok][2048 m]  (emb@W + b_ih1 + b_hh1)
#define OFF_B2   6832128u    // f32  [512 m]
#define OFF_WOT  6834176u    // f32  [256 k][34 v]
#define OFF_C2   6868992u    // f32  [128 u2][128 n]
#define OFF_CTXH 7000064u    // bf16 [128 n][128 k]
#define OFF_CTXL 7032832u
#define OFF_H1H  7065600u    // bf16 [2 buf][128 n][512 k]
#define OFF_H1L  7327744u
#define OFF_H2H  7589888u    // bf16 [2 buf][128 n][128 k]
#define OFF_H2L  7655424u
#define OFF_C1   7720960u    // f32  [512 u][128 n]   (ends 7,983,104)

__device__ __forceinline__ float sigf(float x) { return 1.0f / (1.0f + expf(-x)); }
__device__ __forceinline__ unsigned short f2b(float x) {
  unsigned int u = __float_as_uint(x);
  unsigned int r = (u + 0x7FFFu + ((u >> 16) & 1u)) >> 16;
  return (unsigned short)r;
}
__device__ __forceinline__ float b2f(unsigned short h) {
  return __uint_as_float(((unsigned int)h) << 16);
}

// ---------------- pack kernels ----------------
__global__ __launch_bounds__(256) void pack_w1(const float* __restrict__ Wih1,
                                               const float* __restrict__ Whh1,
                                               unsigned short* __restrict__ W1H,
                                               unsigned short* __restrict__ W1L) {
  int idx = blockIdx.x * 256 + threadIdx.x;     // < 2048*640
  int m = idx / 640, k = idx % 640;
  int u = m >> 2, q = m & 3;
  int g = q * 512 + u;
  float v = (k < 128) ? Wih1[g * 384 + 256 + k] : Whh1[g * 512 + (k - 128)];
  unsigned short hi = f2b(v);
  W1H[idx] = hi;
  W1L[idx] = f2b(v - b2f(hi));
}

__global__ __launch_bounds__(256) void pack_w2(const float* __restrict__ Wih2,
                                               const float* __restrict__ Whh2,
                                               unsigned short* __restrict__ W2H,
                                               unsigned short* __restrict__ W2L) {
  int idx = blockIdx.x * 256 + threadIdx.x;     // < 512*640
  int m = idx / 640, k = idx % 640;
  int u = m >> 2, q = m & 3;
  int g = q * 128 + u;
  float v = (k < 512) ? Wih2[g * 512 + k] : Whh2[g * 128 + (k - 512)];
  unsigned short hi = f2b(v);
  W2H[idx] = hi;
  W2L[idx] = f2b(v - b2f(hi));
}

__global__ __launch_bounds__(256) void pack_eg(const float* __restrict__ emb,
                                               const float* __restrict__ Wih1,
                                               const float* __restrict__ bih1,
                                               const float* __restrict__ bhh1,
                                               float* __restrict__ EG) {
  int idx = blockIdx.x * 256 + threadIdx.x;     // < 34*2048
  int v = idx >> 11, m = idx & 2047;
  int u = m >> 2, q = m & 3;
  int g = q * 512 + u;
  float acc = bih1[g] + bhh1[g];
  const float* e = emb + v * 256;
  const float* w = Wih1 + g * 384;
  for (int k = 0; k < 256; k++) acc += e[k] * w[k];
  EG[idx] = acc;
}

__global__ __launch_bounds__(256) void pack_misc(const float* __restrict__ Wout,
                                                 const float* __restrict__ bih2,
                                                 const float* __restrict__ bhh2,
                                                 float* __restrict__ WoT,
                                                 float* __restrict__ B2) {
  int idx = blockIdx.x * 256 + threadIdx.x;     // < 9216
  if (idx < 8704) {
    int k = idx / 34, v = idx % 34;
    WoT[idx] = Wout[v * 256 + k];
  } else if (idx < 9216) {
    int m = idx - 8704;
    int u = m >> 2, q = m & 3;
    int g = q * 128 + u;
    B2[m] = bih2[g] + bhh2[g];
  }
}

// ---- phase A: 1024 blocks, one 16x16 gate-tile each; validated B-shape mechanics ----
__global__ __launch_bounds__(256) void phaseA_mfma(
    const unsigned short* __restrict__ W1H, const unsigned short* __restrict__ W1L,
    const float* __restrict__ EG, const int* __restrict__ text,
    const unsigned short* __restrict__ CTXH, const unsigned short* __restrict__ CTXL,
    const unsigned short* __restrict__ H1Ho, const unsigned short* __restrict__ H1Lo,
    unsigned short* __restrict__ H1Hn, unsigned short* __restrict__ H1Ln,
    float* __restrict__ C1, int t)
{
  __shared__ float bred[1024];
  const int tid = threadIdx.x, wid = tid >> 6, lane = tid & 63;
  const int l15 = lane & 15, lg = lane >> 4;
  const int mt = blockIdx.x & 127, nt = blockIdx.x >> 7;   // XCD = bid%8 = mt%8
  const int nA = nt * 16 + l15;
  const int kb0 = wid * 160;

  bf16x8 xh[5], xl[5];
#pragma unroll
  for (int ks = 0; ks < 5; ks++) {
    int kb = kb0 + ks * 32;
    if (kb < 128) {
      xh[ks] = *(const bf16x8*)(CTXH + nA * 128 + kb + lg * 8);
      xl[ks] = *(const bf16x8*)(CTXL + nA * 128 + kb + lg * 8);
    } else {
      xh[ks] = *(const bf16x8*)(H1Ho + nA * 512 + (kb - 128) + lg * 8);
      xl[ks] = *(const bf16x8*)(H1Lo + nA * 512 + (kb - 128) + lg * 8);
    }
  }
  const unsigned short* whp = W1H + (size_t)(mt * 16 + l15) * 640 + kb0 + lg * 8;
  const unsigned short* wlp = W1L + (size_t)(mt * 16 + l15) * 640 + kb0 + lg * 8;
  f32x4 a0 = {0.0f, 0.0f, 0.0f, 0.0f};
  f32x4 a1 = {0.0f, 0.0f, 0.0f, 0.0f};
  f32x4 a2 = {0.0f, 0.0f, 0.0f, 0.0f};
#pragma unroll
  for (int ks = 0; ks < 5; ks++) {
    bf16x8 wh_ = *(const bf16x8*)(whp + ks * 32);
    bf16x8 wl_ = *(const bf16x8*)(wlp + ks * 32);
    a0 = __builtin_amdgcn_mfma_f32_16x16x32_bf16(wh_, xh[ks], a0, 0, 0, 0);
    a1 = __builtin_amdgcn_mfma_f32_16x16x32_bf16(wl_, xh[ks], a1, 0, 0, 0);
    a2 = __builtin_amdgcn_mfma_f32_16x16x32_bf16(wh_, xl[ks], a2, 0, 0, 0);
  }
  f32x4 acc = a0 + a1;
  acc = acc + a2;
#pragma unroll
  for (int q = 0; q < 4; q++) bred[q * 256 + wid * 64 + lane] = acc[q];
  __syncthreads();
  if (wid == 0) {
    int tok = text[nA * LDEC + t];
    f32x4 egv = *(const f32x4*)(EG + (size_t)tok * 2048 + mt * 16 + lg * 4);
    float g0 = bred[lane]       + bred[64 + lane]  + bred[128 + lane] + bred[192 + lane] + egv[0];
    float g1 = bred[256 + lane] + bred[320 + lane] + bred[384 + lane] + bred[448 + lane] + egv[1];
    float g2 = bred[512 + lane] + bred[576 + lane] + bred[640 + lane] + bred[704 + lane] + egv[2];
    float g3 = bred[768 + lane] + bred[832 + lane] + bred[896 + lane] + bred[960 + lane] + egv[3];
    float ig = sigf(g0), fg = sigf(g1), gg = tanhf(g2), og = sigf(g3);
    int u = mt * 4 + lg;
    float c = fg * C1[u * 128 + nA] + ig * gg;
    float h = og * tanhf(c);
    C1[u * 128 + nA] = c;
    unsigned short hi = f2b(h);
    H1Hn[nA * 512 + u] = hi;
    H1Ln[nA * 512 + u] = f2b(h - b2f(hi));
  }
}

// ---- phase B: 256 blocks, validated form; c2 in global ----
__global__ __launch_bounds__(256) void phaseB_mfma(
    const unsigned short* __restrict__ W2H, const unsigned short* __restrict__ W2L,
    const float* __restrict__ B2,
    const unsigned short* __restrict__ H1H, const unsigned short* __restrict__ H1L,
    const unsigned short* __restrict__ H2Ho, const unsigned short* __restrict__ H2Lo,
    unsigned short* __restrict__ H2Hn, unsigned short* __restrict__ H2Ln,
    float* __restrict__ C2)
{
  __shared__ float bred[1024];
  const int tid = threadIdx.x, wid = tid >> 6, lane = tid & 63;
  const int l15 = lane & 15, lg = lane >> 4;
  const int mtB = blockIdx.x & 31, ntB = blockIdx.x >> 5;  // XCD = bid%8 = mtB%8
  const int nB = ntB * 16 + l15;
  const int kb0 = wid * 160;

  const unsigned short* x1h = H1H + nB * 512;
  const unsigned short* x1l = H1L + nB * 512;
  const unsigned short* x2h = H2Ho + nB * 128;
  const unsigned short* x2l = H2Lo + nB * 128;
  const unsigned short* whp = W2H + (size_t)(mtB * 16 + l15) * 640 + kb0 + lg * 8;
  const unsigned short* wlp = W2L + (size_t)(mtB * 16 + l15) * 640 + kb0 + lg * 8;
  f32x4 a0 = {0.0f, 0.0f, 0.0f, 0.0f};
  f32x4 a1 = {0.0f, 0.0f, 0.0f, 0.0f};
  f32x4 a2 = {0.0f, 0.0f, 0.0f, 0.0f};
#pragma unroll
  for (int ks = 0; ks < 5; ks++) {
    int kb = kb0 + ks * 32;
    bf16x8 wh_ = *(const bf16x8*)(whp + ks * 32);
    bf16x8 wl_ = *(const bf16x8*)(wlp + ks * 32);
    bf16x8 xh_, xl_;
    if (kb < 512) {
      xh_ = *(const bf16x8*)(x1h + kb + lg * 8);
      xl_ = *(const bf16x8*)(x1l + kb + lg * 8);
    } else {
      xh_ = *(const bf16x8*)(x2h + kb - 512 + lg * 8);
      xl_ = *(const bf16x8*)(x2l + kb - 512 + lg * 8);
    }
    a0 = __builtin_amdgcn_mfma_f32_16x16x32_bf16(wh_, xh_, a0, 0, 0, 0);
    a1 = __builtin_amdgcn_mfma_f32_16x16x32_bf16(wl_, xh_, a1, 0, 0, 0);
    a2 = __builtin_amdgcn_mfma_f32_16x16x32_bf16(wh_, xl_, a2, 0, 0, 0);
  }
  f32x4 acc = a0 + a1;
  acc = acc + a2;
#pragma unroll
  for (int q = 0; q < 4; q++) bred[q * 256 + wid * 64 + lane] = acc[q];
  __syncthreads();
  if (wid == 0) {
    f32x4 b2v = *(const f32x4*)(B2 + mtB * 16 + lg * 4);
    float g0 = bred[lane]       + bred[64 + lane]  + bred[128 + lane] + bred[192 + lane] + b2v[0];
    float g1 = bred[256 + lane] + bred[320 + lane] + bred[384 + lane] + bred[448 + lane] + b2v[1];
    float g2 = bred[512 + lane] + bred[576 + lane] + bred[640 + lane] + bred[704 + lane] + b2v[2];
    float g3 = bred[768 + lane] + bred[832 + lane] + bred[896 + lane] + bred[960 + lane] + b2v[3];
    int u = mtB * 4 + lg;
    float c = sigf(g1) * C2[u * 128 + nB] + sigf(g0) * tanhf(g2);
    float h = sigf(g3) * tanhf(c);
    C2[u * 128 + nB] = c;
    unsigned short hi = f2b(h);
    H2Hn[nB * 128 + u] = hi;
    H2Ln[nB * 128 + u] = f2b(h - b2f(hi));
  }
}

// ---- phase C: attention + projection (R1-proven fp32), 128 blocks ----
__global__ __launch_bounds__(256) void phaseC(
    const float* __restrict__ key, const float* __restrict__ values,
    const int* __restrict__ lens,
    const unsigned short* __restrict__ H2H, const unsigned short* __restrict__ H2L,
    const float* __restrict__ WoT, const float* __restrict__ bout,
    unsigned short* __restrict__ CTXH, unsigned short* __restrict__ CTXL,
    float* __restrict__ out, int t)
{
  __shared__ float h2s[128];
  __shared__ float es[512];
  __shared__ float red[256];
  __shared__ float ctxs[128];
  __shared__ float pr[68];
  int n = blockIdx.x, tid = threadIdx.x;
  int len = lens[n];
  if (tid < 128) h2s[tid] = b2f(H2H[n * 128 + tid]) + b2f(H2L[n * 128 + tid]);
  __syncthreads();
  float lmax = -1e30f;
  for (int tt = tid; tt < len; tt += 256) {
    const float4* kr = (const float4*)(key + ((size_t)tt * 128 + n) * 128);
    float acc = 0.0f;
#pragma unroll 8
    for (int k = 0; k < 32; k++) {
      float4 kv = kr[k];
      acc += kv.x * h2s[4 * k] + kv.y * h2s[4 * k + 1] + kv.z * h2s[4 * k + 2] + kv.w * h2s[4 * k + 3];
    }
    es[tt] = acc;
    lmax = fmaxf(lmax, acc);
  }
  red[tid] = lmax; __syncthreads();
  for (int s = 128; s > 0; s >>= 1) { if (tid < s) red[tid] = fmaxf(red[tid], red[tid + s]); __syncthreads(); }
  float m = red[0];
  __syncthreads();
  float lsum = 0.0f;
  for (int tt = tid; tt < len; tt += 256) {
    float p = expf(es[tt] - m);
    es[tt] = p;
    lsum += p;
  }
  red[tid] = lsum; __syncthreads();
  for (int s = 128; s > 0; s >>= 1) { if (tid < s) red[tid] += red[tid + s]; __syncthreads(); }
  float S = red[0];
  __syncthreads();
  {
    int v = tid & 127, tpar = tid >> 7;
    float acc = 0.0f;
    for (int tt = tpar; tt < len; tt += 2) {
      acc += es[tt] * values[((size_t)tt * 128 + n) * 128 + v];
    }
    red[tid] = acc;
  }
  __syncthreads();
  if (tid < 128) {
    float cv = (red[tid] + red[tid + 128]) / S;
    ctxs[tid] = cv;
    unsigned short hi = f2b(cv);
    CTXH[n * 128 + tid] = hi;
    CTXL[n * 128 + tid] = f2b(cv - b2f(hi));
  }
  __syncthreads();
  if (tid < 68) {
    int vv = tid % 34, part = tid / 34;
    const float* src = part ? ctxs : h2s;
    const float* wcol = WoT + (part ? 128 * 34 : 0);
    float a = 0.0f;
#pragma unroll 8
    for (int k2 = 0; k2 < 128; k2++) a += src[k2] * wcol[k2 * 34 + vv];
    pr[tid] = a;
  }
  __syncthreads();
  if (tid < 34) {
    out[(size_t)n * (LDEC * VOCD) + t * VOCD + tid] = bout[tid] + pr[tid] + pr[34 + tid];
  }
}

extern "C" void kernel_launch(void* const* d_in, const int* in_sizes, int n_in,
                              void* d_out, int out_size, void* d_ws, size_t ws_size,
                              hipStream_t stream) {
  const float* key    = (const float*)d_in[0];
  const float* values = (const float*)d_in[1];
  const int*   lens   = (const int*)d_in[2];
  const int*   text   = (const int*)d_in[3];
  const float* emb    = (const float*)d_in[4];
  const float* Wih1   = (const float*)d_in[5];
  const float* Whh1   = (const float*)d_in[6];
  const float* bih1   = (const float*)d_in[7];
  const float* bhh1   = (const float*)d_in[8];
  const float* Wih2   = (const float*)d_in[9];
  const float* Whh2   = (const float*)d_in[10];
  const float* bih2   = (const float*)d_in[11];
  const float* bhh2   = (const float*)d_in[12];
  const float* Wout   = (const float*)d_in[13];
  const float* bout   = (const float*)d_in[14];

  char* ws = (char*)d_ws;
  unsigned short* W1H = (unsigned short*)(ws + OFF_W1H);
  unsigned short* W1L = (unsigned short*)(ws + OFF_W1L);
  unsigned short* W2H = (unsigned short*)(ws + OFF_W2H);
  unsigned short* W2L = (unsigned short*)(ws + OFF_W2L);
  float* EG   = (float*)(ws + OFF_EG);
  float* B2   = (float*)(ws + OFF_B2);
  float* WoT  = (float*)(ws + OFF_WOT);
  float* C2   = (float*)(ws + OFF_C2);
  unsigned short* CTXH = (unsigned short*)(ws + OFF_CTXH);
  unsigned short* CTXL = (unsigned short*)(ws + OFF_CTXL);
  unsigned short* H1H  = (unsigned short*)(ws + OFF_H1H);
  unsigned short* H1L  = (unsigned short*)(ws + OFF_H1L);
  unsigned short* H2H  = (unsigned short*)(ws + OFF_H2H);
  unsigned short* H2L  = (unsigned short*)(ws + OFF_H2L);
  float* C1   = (float*)(ws + OFF_C1);
  float* out  = (float*)d_out;

  // init recurrent state: ctx=0, c1=c2=0, h1(-1)=0 (buf1), h2(-1)=0 (buf1)
  hipMemsetAsync(CTXH, 0, 32768, stream);
  hipMemsetAsync(CTXL, 0, 32768, stream);
  hipMemsetAsync(C1,   0, 262144, stream);
  hipMemsetAsync(C2,   0, 65536, stream);
  hipMemsetAsync((char*)H1H + 131072, 0, 131072, stream);
  hipMemsetAsync((char*)H1L + 131072, 0, 131072, stream);
  hipMemsetAsync((char*)H2H + 32768, 0, 32768, stream);
  hipMemsetAsync((char*)H2L + 32768, 0, 32768, stream);

  pack_w1  <<<5120, 256, 0, stream>>>(Wih1, Whh1, W1H, W1L);
  pack_w2  <<<1280, 256, 0, stream>>>(Wih2, Whh2, W2H, W2L);
  pack_eg  <<<272,  256, 0, stream>>>(emb, Wih1, bih1, bhh1, EG);
  pack_misc<<<36,   256, 0, stream>>>(Wout, bih2, bhh2, WoT, B2);

  for (int t = 0; t < LDEC; t++) {
    const int wp = t & 1, rp = (t + 1) & 1;
    unsigned short* h1ho = H1H + rp * 65536;
    unsigned short* h1lo = H1L + rp * 65536;
    unsigned short* h1hn = H1H + wp * 65536;
    unsigned short* h1ln = H1L + wp * 65536;
    unsigned short* h2ho = H2H + rp * 16384;
    unsigned short* h2lo = H2L + rp * 16384;
    unsigned short* h2hn = H2H + wp * 16384;
    unsigned short* h2ln = H2L + wp * 16384;

    phaseA_mfma<<<1024, 256, 0, stream>>>(W1H, W1L, EG, text, CTXH, CTXL,
                                          h1ho, h1lo, h1hn, h1ln, C1, t);
    phaseB_mfma<<<256, 256, 0, stream>>>(W2H, W2L, B2, h1hn, h1ln,
                                         h2ho, h2lo, h2hn, h2ln, C2);
    phaseC<<<128, 256, 0, stream>>>(key, values, lens, h2hn, h2ln,
                                    WoT, bout, CTXH, CTXL, out, t);
  }
}